// Round 2
// baseline (557.016 us; speedup 1.0000x reference)
//
#include <hip/hip_runtime.h>
#include <math.h>

#define B_ 32
#define HW_ 4096
#define N_ 16
#define C_ 128
#define F_ 512
#define ITERS_ 3
#define EPS_LN 1e-5f
#define EPS_ATTN 1e-5f

typedef __attribute__((ext_vector_type(8))) short short8;
typedef __attribute__((ext_vector_type(4))) float f32x4;

static __device__ __forceinline__ unsigned short f2b(float f) {
    union { float f; unsigned u; } v; v.f = f;
    unsigned r = v.u + 0x7fffu + ((v.u >> 16) & 1u);
    return (unsigned short)(r >> 16);
}

// ---------------------------------------------------------------------------
// One-time: Wk, Wv fp32 -> bf16 (row-major [c_out][c_in])
// ---------------------------------------------------------------------------
__global__ __launch_bounds__(256) void k_wprep(
    const float* __restrict__ Wk, const float* __restrict__ Wv,
    unsigned short* __restrict__ Wk_bf, unsigned short* __restrict__ Wv_bf)
{
    int t = blockIdx.x * 256 + threadIdx.x;   // 4096 threads, one float4 each
    float4 a = ((const float4*)Wk)[t];
    float4 b = ((const float4*)Wv)[t];
    unsigned alo = (unsigned)f2b(a.x) | ((unsigned)f2b(a.y) << 16);
    unsigned ahi = (unsigned)f2b(a.z) | ((unsigned)f2b(a.w) << 16);
    unsigned blo = (unsigned)f2b(b.x) | ((unsigned)f2b(b.y) << 16);
    unsigned bhi = (unsigned)f2b(b.z) | ((unsigned)f2b(b.w) << 16);
    ((unsigned*)Wk_bf)[t * 2]     = alo;
    ((unsigned*)Wk_bf)[t * 2 + 1] = ahi;
    ((unsigned*)Wv_bf)[t * 2]     = blo;
    ((unsigned*)Wv_bf)[t * 2 + 1] = bhi;
}

// ---------------------------------------------------------------------------
// Kernel 1: kv = LN(inp); K = kv@Wk^T -> bf16 [b][hw][c];
//           V = kv@Wv^T -> bf16 transposed [b][c][hw]
// 64 rows/block, 256 threads. Weights read as B-frags straight from global
// (bf16, L1-resident). LDS = A tile only (17.4 KB) -> 8 blocks/CU.
// ---------------------------------------------------------------------------
__global__ __launch_bounds__(256) void k_kvproj(
    const float* __restrict__ inp, const float* __restrict__ lng,
    const float* __restrict__ lnb, const unsigned short* __restrict__ Wk_bf,
    const unsigned short* __restrict__ Wv_bf, unsigned short* __restrict__ Kbf,
    unsigned short* __restrict__ Vt)
{
    __shared__ __align__(16) unsigned short A_lds[64 * 136];   // also V-transpose buf
    const int tid = threadIdx.x;
    const int wave = tid >> 6, lane = tid & 63;
    const int l15 = lane & 15, q4 = lane >> 4;
    const int kof = q4 * 8;
    const int tile0 = blockIdx.x * 64;
    const int b = tile0 >> 12;
    const int hwbase = tile0 & (HW_ - 1);

    // ---- LN stage: 4 threads per row, 32 elems each ----
    {
        int r = tid >> 2, part = tid & 3;
        int row = tile0 + r;
        const float4* x4 = (const float4*)(inp + row * C_ + part * 32);
        float4 xv[8];
        float s = 0.f, ss = 0.f;
#pragma unroll
        for (int i = 0; i < 8; i++) {
            xv[i] = x4[i];
            s += xv[i].x + xv[i].y + xv[i].z + xv[i].w;
            ss += xv[i].x * xv[i].x + xv[i].y * xv[i].y + xv[i].z * xv[i].z + xv[i].w * xv[i].w;
        }
        s += __shfl_xor(s, 1);  s += __shfl_xor(s, 2);
        ss += __shfl_xor(ss, 1); ss += __shfl_xor(ss, 2);
        float mean = s * (1.f / 128.f);
        float var = ss * (1.f / 128.f) - mean * mean;
        float rstd = rsqrtf(var + EPS_LN);
        const float4* g4 = (const float4*)(lng + part * 32);
        const float4* b4 = (const float4*)(lnb + part * 32);
        unsigned* Au = (unsigned*)A_lds;
        int ubase = r * 68 + part * 16;
#pragma unroll
        for (int i = 0; i < 8; i++) {
            float4 gg = g4[i], bb = b4[i];
            float n0 = (xv[i].x - mean) * rstd * gg.x + bb.x;
            float n1 = (xv[i].y - mean) * rstd * gg.y + bb.y;
            float n2 = (xv[i].z - mean) * rstd * gg.z + bb.z;
            float n3 = (xv[i].w - mean) * rstd * gg.w + bb.w;
            Au[ubase + i * 2]     = (unsigned)f2b(n0) | ((unsigned)f2b(n1) << 16);
            Au[ubase + i * 2 + 1] = (unsigned)f2b(n2) | ((unsigned)f2b(n3) << 16);
        }
    }
    __syncthreads();

    const int m_row = (wave << 4) + l15;
    short8 af[4];
#pragma unroll
    for (int ks = 0; ks < 4; ks++)
        af[ks] = *(const short8*)&A_lds[m_row * 136 + ks * 32 + kof];

    f32x4 acc[8];
    // ---- K phase (B-frags from global Wk_bf) ----
#pragma unroll
    for (int nt = 0; nt < 8; nt++) {
        acc[nt] = (f32x4){0.f, 0.f, 0.f, 0.f};
#pragma unroll
        for (int ks = 0; ks < 4; ks++) {
            short8 bf = *(const short8*)&Wk_bf[(nt * 16 + l15) * 128 + ks * 32 + kof];
            acc[nt] = __builtin_amdgcn_mfma_f32_16x16x32_bf16(af[ks], bf, acc[nt], 0, 0, 0);
        }
    }
    {
        int hwr0 = hwbase + (wave << 4);
#pragma unroll
        for (int nt = 0; nt < 8; nt++) {
            int c = nt * 16 + l15;
#pragma unroll
            for (int i = 0; i < 4; i++) {
                int m = (q4 << 2) + i;
                Kbf[(b * HW_ + hwr0 + m) * C_ + c] = f2b(acc[nt][i]);
            }
        }
    }
    // ---- V phase ----
#pragma unroll
    for (int nt = 0; nt < 8; nt++) {
        acc[nt] = (f32x4){0.f, 0.f, 0.f, 0.f};
#pragma unroll
        for (int ks = 0; ks < 4; ks++) {
            short8 bf = *(const short8*)&Wv_bf[(nt * 16 + l15) * 128 + ks * 32 + kof];
            acc[nt] = __builtin_amdgcn_mfma_f32_16x16x32_bf16(af[ks], bf, acc[nt], 0, 0, 0);
        }
    }
    __syncthreads();   // all waves done with A_lds; reuse as transpose buffer
    {
        unsigned short* Vl = A_lds;  // [64 hw][stride 130]
#pragma unroll
        for (int nt = 0; nt < 8; nt++) {
            int c = nt * 16 + l15;
#pragma unroll
            for (int i = 0; i < 4; i++) {
                int m = (wave << 4) + (q4 << 2) + i;
                Vl[m * 130 + c] = f2b(acc[nt][i]);
            }
        }
    }
    __syncthreads();
    {
        const unsigned short* Vl = A_lds;
        int c = tid >> 1, h0 = (tid & 1) * 32;
        int base = (b * C_ + c) * HW_ + hwbase + h0;
#pragma unroll
        for (int i = 0; i < 16; i++) {
            unsigned lo = Vl[(h0 + 2 * i) * 130 + c];
            unsigned hi = Vl[(h0 + 2 * i + 1) * 130 + c];
            *(unsigned*)&Vt[base + 2 * i] = lo | (hi << 16);
        }
    }
}

// ---------------------------------------------------------------------------
// Kernel 2 (per iter): fused qn-prep + logits -> column softmax -> a0 ->
// per-chunk partial U / rowsum (NO atomics). grid (16, 32): 256 hw per block,
// 64 hw per wave. qn computed redundantly per block (cheap).
// ---------------------------------------------------------------------------
__global__ __launch_bounds__(256) void k_attn(
    const float* __restrict__ qsrc, const float* __restrict__ lng,
    const float* __restrict__ lnb, const float* __restrict__ Wq,
    const unsigned short* __restrict__ Kbf, const unsigned short* __restrict__ Vt,
    float* __restrict__ Upart, float* __restrict__ rspart,
    float* __restrict__ a0_out, int last)
{
    __shared__ __align__(16) char smem[32768 + 4352 + 9216 + 256];
    float* xq = (float*)smem;                                   // 16*128 f32 (phase 1)
    float* Ul = (float*)smem;                                   // 4*2048 f32 (phase 3)
    unsigned short* qn_l = (unsigned short*)(smem + 32768);     // 16*136 bf16
    unsigned short* Pb   = (unsigned short*)(smem + 32768 + 4352); // 4 waves * 16*72 bf16
    float* rsw = (float*)(smem + 32768 + 4352 + 9216);          // 4*16 f32

    const int b = blockIdx.y, chunk = blockIdx.x;
    const int tid = threadIdx.x;
    const int wave = tid >> 6, lane = tid & 63;
    const int l15 = lane & 15, q4 = lane >> 4;
    const int kof = q4 * 8;
    const int hwb = chunk * 256 + wave * 64;

    // ---- qn = (LN(q)*g+b) @ Wq^T * scale -> LDS bf16 ----
    {
        int n = tid >> 4, part = tid & 15;
        const float4* x4 = (const float4*)(qsrc + (b * 16 + n) * 128 + part * 8);
        float4 x0 = x4[0], x1 = x4[1];
        float s = x0.x + x0.y + x0.z + x0.w + x1.x + x1.y + x1.z + x1.w;
        float ss = x0.x * x0.x + x0.y * x0.y + x0.z * x0.z + x0.w * x0.w +
                   x1.x * x1.x + x1.y * x1.y + x1.z * x1.z + x1.w * x1.w;
        s += __shfl_xor(s, 1); s += __shfl_xor(s, 2); s += __shfl_xor(s, 4); s += __shfl_xor(s, 8);
        ss += __shfl_xor(ss, 1); ss += __shfl_xor(ss, 2); ss += __shfl_xor(ss, 4); ss += __shfl_xor(ss, 8);
        float mean = s * (1.f / 128.f);
        float var = ss * (1.f / 128.f) - mean * mean;
        float rstd = rsqrtf(var + EPS_LN);
        const float4* g4 = (const float4*)(lng + part * 8);
        const float4* b4 = (const float4*)(lnb + part * 8);
        float4 g0 = g4[0], g1 = g4[1], bb0 = b4[0], bb1 = b4[1];
        float4 o0, o1;
        o0.x = (x0.x - mean) * rstd * g0.x + bb0.x;
        o0.y = (x0.y - mean) * rstd * g0.y + bb0.y;
        o0.z = (x0.z - mean) * rstd * g0.z + bb0.z;
        o0.w = (x0.w - mean) * rstd * g0.w + bb0.w;
        o1.x = (x1.x - mean) * rstd * g1.x + bb1.x;
        o1.y = (x1.y - mean) * rstd * g1.y + bb1.y;
        o1.z = (x1.z - mean) * rstd * g1.z + bb1.z;
        o1.w = (x1.w - mean) * rstd * g1.w + bb1.w;
        float4* xrow = (float4*)&xq[n * 128];
        xrow[part * 2] = o0;
        xrow[part * 2 + 1] = o1;
    }
    __syncthreads();
    {
        int n = tid >> 4, part = tid & 15;
        float o[8] = {0.f, 0.f, 0.f, 0.f, 0.f, 0.f, 0.f, 0.f};
        const float4* xv4 = (const float4*)&xq[n * 128];
#pragma unroll 4
        for (int j = 0; j < 32; j++) {
            float4 xv = xv4[j];
#pragma unroll
            for (int i = 0; i < 8; i++) {
                float4 w = ((const float4*)(Wq + (part * 8 + i) * 128))[j];
                o[i] += w.x * xv.x + w.y * xv.y + w.z * xv.z + w.w * xv.w;
            }
        }
        const float scale = 0.08838834764831845f;  // 128^-0.5
        __syncthreads();  // xq reads done before qn_l write overlaps nothing; order barrier
#pragma unroll
        for (int i = 0; i < 8; i++)
            qn_l[n * 136 + part * 8 + i] = f2b(o[i] * scale);
    }
    __syncthreads();

    short8 aq[4];
#pragma unroll
    for (int ks = 0; ks < 4; ks++)
        aq[ks] = *(const short8*)&qn_l[l15 * 136 + ks * 32 + kof];

    // ---- scores + column softmax over 16 slots; 4 hw-tiles of 16 per wave ----
    float rs[4] = {0.f, 0.f, 0.f, 0.f};
    unsigned short* Pw = Pb + wave * 16 * 72;
#pragma unroll
    for (int s = 0; s < 4; s++) {
        int hwt = hwb + s * 16;
        f32x4 sa = {0.f, 0.f, 0.f, 0.f};
#pragma unroll
        for (int ks = 0; ks < 4; ks++) {
            short8 bk = *(const short8*)&Kbf[(b * HW_ + hwt + l15) * C_ + ks * 32 + kof];
            sa = __builtin_amdgcn_mfma_f32_16x16x32_bf16(aq[ks], bk, sa, 0, 0, 0);
        }
        float mx = fmaxf(fmaxf(sa[0], sa[1]), fmaxf(sa[2], sa[3]));
        mx = fmaxf(mx, __shfl_xor(mx, 16));
        mx = fmaxf(mx, __shfl_xor(mx, 32));
        float e[4]; float ssum = 0.f;
#pragma unroll
        for (int i = 0; i < 4; i++) { e[i] = __expf(sa[i] - mx); ssum += e[i]; }
        ssum += __shfl_xor(ssum, 16);
        ssum += __shfl_xor(ssum, 32);
        float inv = 1.f / ssum;
#pragma unroll
        for (int i = 0; i < 4; i++) {
            float a0v = e[i] * inv;
            rs[i] += a0v;
            if (last) a0_out[(b * 16 + q4 * 4 + i) * HW_ + hwt + l15] = a0v;
            Pw[(q4 * 4 + i) * 72 + s * 16 + l15] = f2b(a0v);
        }
    }
    // rowsum wave partials
#pragma unroll
    for (int i = 0; i < 4; i++) {
        rs[i] += __shfl_xor(rs[i], 1);
        rs[i] += __shfl_xor(rs[i], 2);
        rs[i] += __shfl_xor(rs[i], 4);
        rs[i] += __shfl_xor(rs[i], 8);
    }
    if (l15 == 0) {
#pragma unroll
        for (int i = 0; i < 4; i++) rsw[wave * 16 + q4 * 4 + i] = rs[i];
    }
    __syncthreads();

    // ---- u^T partial: D[c][q] = sum_hw Vt[c][hw] * a0[q][hw], this wave's 64 hw
    f32x4 uacc[8];
#pragma unroll
    for (int ct = 0; ct < 8; ct++) {
        uacc[ct] = (f32x4){0.f, 0.f, 0.f, 0.f};
#pragma unroll
        for (int k2 = 0; k2 < 2; k2++) {
            short8 av = *(const short8*)&Vt[(b * C_ + ct * 16 + l15) * HW_ + hwb + k2 * 32 + kof];
            short8 bp = *(const short8*)&Pw[l15 * 72 + k2 * 32 + kof];
            uacc[ct] = __builtin_amdgcn_mfma_f32_16x16x32_bf16(av, bp, uacc[ct], 0, 0, 0);
        }
    }
    // stash per-wave partials (xq region is dead -> Ul overlay)
#pragma unroll
    for (int ct = 0; ct < 8; ct++) {
        int c = ct * 16 + q4 * 4;
#pragma unroll
        for (int i = 0; i < 4; i++)
            Ul[wave * 2048 + (c + i) * 16 + l15] = uacc[ct][i];
    }
    __syncthreads();
    {
        float* up = Upart + (b * 16 + chunk) * 2048;
#pragma unroll
        for (int k = 0; k < 8; k++) {
            int idx = tid + k * 256;          // idx = c*16 + q
            up[idx] = Ul[idx] + Ul[2048 + idx] + Ul[4096 + idx] + Ul[6144 + idx];
        }
        if (tid < 16)
            rspart[(b * 16 + chunk) * 16 + tid] =
                rsw[tid] + rsw[16 + tid] + rsw[32 + tid] + rsw[48 + tid];
    }
}

// ---------------------------------------------------------------------------
// Kernel 3 (per iter): u = (sum Upart)/(sum rspart + eps); y = GRU(u, h);
// z = LN2(y); q_new = y + FFN(z). 2 rows per block, 256 threads. fp32.
// ---------------------------------------------------------------------------
__global__ __launch_bounds__(256) void k_tail(
    const float* __restrict__ Upart, const float* __restrict__ rspart,
    const float* __restrict__ hsrc, float* __restrict__ q_buf,
    const float* __restrict__ wih, const float* __restrict__ whh,
    const float* __restrict__ bih, const float* __restrict__ bhh,
    const float* __restrict__ ln2g, const float* __restrict__ ln2b,
    const float* __restrict__ w1, const float* __restrict__ b1,
    const float* __restrict__ w2, const float* __restrict__ b2,
    float* __restrict__ out_q, int last)
{
    __shared__ __align__(16) float u_l[2][128];
    __shared__ __align__(16) float h_l[2][128];
    __shared__ __align__(16) float g_l[2][768];
    __shared__ __align__(16) float z_l[2][128];
    __shared__ __align__(16) float y_l[2][128];
    __shared__ __align__(16) float h1_l[2][512];
    __shared__ float stats[2][2];
    int tid = threadIdx.x;
    int row0 = blockIdx.x * 2;
    {
        int r = tid >> 7, c = tid & 127;
        int row = row0 + r;
        int bb = row >> 4, q = row & 15;
        float rsv = 0.f, uraw = 0.f;
#pragma unroll
        for (int ch = 0; ch < 16; ch++) {
            rsv  += rspart[(bb * 16 + ch) * 16 + q];
            uraw += Upart[(bb * 16 + ch) * 2048 + c * 16 + q];
        }
        u_l[r][c] = uraw / (rsv + EPS_ATTN);
        h_l[r][c] = hsrc[row * 128 + c];
    }
    __syncthreads();
#pragma unroll
    for (int o3 = 0; o3 < 3; o3++) {
        int o = tid + o3 * 256;
        const float* wrow;
        const float* srcbase;
        float bias;
        if (o < 384) { wrow = wih + o * 128; srcbase = &u_l[0][0]; bias = bih[o]; }
        else         { wrow = whh + (o - 384) * 128; srcbase = &h_l[0][0]; bias = bhh[o - 384]; }
        const float4* w4 = (const float4*)wrow;
        const float4* s0 = (const float4*)srcbase;
        const float4* s1 = (const float4*)(srcbase + 128);
        float a0acc = 0.f, a1acc = 0.f;
#pragma unroll 8
        for (int j = 0; j < 32; j++) {
            float4 w = w4[j], a = s0[j], bb = s1[j];
            a0acc += w.x * a.x + w.y * a.y + w.z * a.z + w.w * a.w;
            a1acc += w.x * bb.x + w.y * bb.y + w.z * bb.z + w.w * bb.w;
        }
        g_l[0][o] = a0acc + bias;
        g_l[1][o] = a1acc + bias;
    }
    __syncthreads();
    {
        int r = tid >> 7, c = tid & 127;
        float ir = g_l[r][c], iz = g_l[r][128 + c], in_ = g_l[r][256 + c];
        float hr = g_l[r][384 + c], hz = g_l[r][512 + c], hn = g_l[r][640 + c];
        float rr = 1.f / (1.f + expf(-(ir + hr)));
        float zz = 1.f / (1.f + expf(-(iz + hz)));
        float nn = tanhf(in_ + rr * hn);
        y_l[r][c] = (1.f - zz) * nn + zz * h_l[r][c];
    }
    __syncthreads();
    if (tid < 128) {
        int w = tid >> 6, lane = tid & 63;
        float v0 = y_l[w][lane], v1 = y_l[w][lane + 64];
        float s = v0 + v1, ss = v0 * v0 + v1 * v1;
#pragma unroll
        for (int off = 1; off < 64; off <<= 1) {
            s += __shfl_xor(s, off);
            ss += __shfl_xor(ss, off);
        }
        if (lane == 0) {
            float mean = s * (1.f / 128.f);
            float var = ss * (1.f / 128.f) - mean * mean;
            stats[w][0] = mean;
            stats[w][1] = rsqrtf(var + EPS_LN);
        }
    }
    __syncthreads();
    {
        int r = tid >> 7, c = tid & 127;
        z_l[r][c] = (y_l[r][c] - stats[r][0]) * stats[r][1] * ln2g[c] + ln2b[c];
    }
    __syncthreads();
#pragma unroll
    for (int f2i = 0; f2i < 2; f2i++) {
        int f = tid + f2i * 256;
        const float4* w4 = (const float4*)(w1 + f * 128);
        const float4* s0 = (const float4*)&z_l[0][0];
        const float4* s1 = (const float4*)&z_l[1][0];
        float a0acc = 0.f, a1acc = 0.f;
#pragma unroll 8
        for (int j = 0; j < 32; j++) {
            float4 w = w4[j], a = s0[j], bb = s1[j];
            a0acc += w.x * a.x + w.y * a.y + w.z * a.z + w.w * a.w;
            a1acc += w.x * bb.x + w.y * bb.y + w.z * bb.z + w.w * bb.w;
        }
        float bv = b1[f];
        h1_l[0][f] = fmaxf(a0acc + bv, 0.f);
        h1_l[1][f] = fmaxf(a1acc + bv, 0.f);
    }
    __syncthreads();
    {
        int r = tid >> 7, c = tid & 127;
        const float4* w4 = (const float4*)(w2 + c * 512);
        const float4* hh = (const float4*)&h1_l[r][0];
        float acc = 0.f;
#pragma unroll 8
        for (int j = 0; j < 128; j++) {
            float4 w = w4[j], v = hh[j];
            acc += w.x * v.x + w.y * v.y + w.z * v.z + w.w * v.w;
        }
        float q_new = y_l[r][c] + acc + b2[c];
        int row = row0 + r;
        q_buf[row * 128 + c] = q_new;
        if (last) out_q[row * 128 + c] = q_new;
    }
}

// ---------------------------------------------------------------------------
extern "C" void kernel_launch(void* const* d_in, const int* in_sizes, int n_in,
                              void* d_out, int out_size, void* d_ws, size_t ws_size,
                              hipStream_t stream) {
    const float* inp     = (const float*)d_in[0];
    const float* query   = (const float*)d_in[1];
    const float* ln_kv_g = (const float*)d_in[2];
    const float* ln_kv_b = (const float*)d_in[3];
    const float* Wk      = (const float*)d_in[4];
    const float* Wv      = (const float*)d_in[5];
    const float* ln_q_g  = (const float*)d_in[6];
    const float* ln_q_b  = (const float*)d_in[7];
    const float* Wq      = (const float*)d_in[8];
    const float* gru_wih = (const float*)d_in[9];
    const float* gru_whh = (const float*)d_in[10];
    const float* gru_bih = (const float*)d_in[11];
    const float* gru_bhh = (const float*)d_in[12];
    const float* ln2_g   = (const float*)d_in[13];
    const float* ln2_b   = (const float*)d_in[14];
    const float* ffn_w1  = (const float*)d_in[15];
    const float* ffn_b1  = (const float*)d_in[16];
    const float* ffn_w2  = (const float*)d_in[17];
    const float* ffn_b2  = (const float*)d_in[18];

    char* ws = (char*)d_ws;
    unsigned short* Kbf   = (unsigned short*)ws;                  // 33554432
    unsigned short* Vt    = (unsigned short*)(ws + 33554432);     // 33554432
    float* q_buf          = (float*)(ws + 67108864);              // 262144
    float* Upart          = (float*)(ws + 67371008);              // 4194304
    float* rspart         = (float*)(ws + 71565312);              // 32768
    unsigned short* Wk_bf = (unsigned short*)(ws + 71598080);     // 32768
    unsigned short* Wv_bf = (unsigned short*)(ws + 71630848);     // 32768

    float* out_q  = (float*)d_out;
    float* out_a0 = out_q + B_ * N_ * C_;

    k_wprep<<<dim3(16), dim3(256), 0, stream>>>(Wk, Wv, Wk_bf, Wv_bf);
    k_kvproj<<<dim3((B_ * HW_) / 64), dim3(256), 0, stream>>>(
        inp, ln_kv_g, ln_kv_b, Wk_bf, Wv_bf, Kbf, Vt);

    for (int it = 0; it < ITERS_; it++) {
        const float* qsrc = (it == 0) ? query : q_buf;
        k_attn<<<dim3(16, B_), dim3(256), 0, stream>>>(
            qsrc, ln_q_g, ln_q_b, Wq, Kbf, Vt, Upart, rspart,
            out_a0, it == ITERS_ - 1 ? 1 : 0);
        k_tail<<<dim3((B_ * N_) / 2), dim3(256), 0, stream>>>(
            Upart, rspart, qsrc, q_buf, gru_wih, gru_whh, gru_bih, gru_bhh,
            ln2_g, ln2_b, ffn_w1, ffn_b1, ffn_w2, ffn_b2,
            out_q, it == ITERS_ - 1 ? 1 : 0);
    }
}

// Round 3
// 342.289 us; speedup vs baseline: 1.6273x; 1.6273x over previous
//
#include <hip/hip_runtime.h>
#include <math.h>

#define B_ 32
#define HW_ 4096
#define N_ 16
#define C_ 128
#define F_ 512
#define ITERS_ 3
#define EPS_LN 1e-5f
#define EPS_ATTN 1e-5f

typedef __attribute__((ext_vector_type(8))) short short8;
typedef __attribute__((ext_vector_type(4))) float f32x4;

static __device__ __forceinline__ unsigned short f2b(float f) {
    union { float f; unsigned u; } v; v.f = f;
    unsigned r = v.u + 0x7fffu + ((v.u >> 16) & 1u);
    return (unsigned short)(r >> 16);
}
static __device__ __forceinline__ float blo(unsigned u) {
    union { unsigned u; float f; } v; v.u = u << 16; return v.f;
}
static __device__ __forceinline__ float bhi(unsigned u) {
    union { unsigned u; float f; } v; v.u = u & 0xffff0000u; return v.f;
}

// ---------------------------------------------------------------------------
// One-time: convert Wk, Wv, gru_wih, gru_whh, ffn_w1, ffn_w2 fp32 -> bf16.
// 65536 float4 groups total, 256 blocks x 256 threads.
// ---------------------------------------------------------------------------
__global__ __launch_bounds__(256) void k_wprep(
    const float* __restrict__ Wk, const float* __restrict__ Wv,
    const float* __restrict__ wih, const float* __restrict__ whh,
    const float* __restrict__ w1, const float* __restrict__ w2,
    unsigned short* __restrict__ Wk_bf, unsigned short* __restrict__ Wv_bf,
    unsigned short* __restrict__ wih_bf, unsigned short* __restrict__ whh_bf,
    unsigned short* __restrict__ w1_bf, unsigned short* __restrict__ w2_bf)
{
    int t = blockIdx.x * 256 + threadIdx.x;   // float4 index
    const float* src; unsigned short* dst; int off;
    if (t < 4096)       { src = Wk;  dst = Wk_bf;  off = t; }
    else if (t < 8192)  { src = Wv;  dst = Wv_bf;  off = t - 4096; }
    else if (t < 20480) { src = wih; dst = wih_bf; off = t - 8192; }
    else if (t < 32768) { src = whh; dst = whh_bf; off = t - 20480; }
    else if (t < 49152) { src = w1;  dst = w1_bf;  off = t - 32768; }
    else                { src = w2;  dst = w2_bf;  off = t - 49152; }
    float4 a = ((const float4*)src)[off];
    unsigned lo = (unsigned)f2b(a.x) | ((unsigned)f2b(a.y) << 16);
    unsigned hi = (unsigned)f2b(a.z) | ((unsigned)f2b(a.w) << 16);
    uint2 p; p.x = lo; p.y = hi;
    *(uint2*)(dst + off * 4) = p;
}

// ---------------------------------------------------------------------------
// One-time: qn_0 = (LN(query)*g+b) @ Wq^T * scale -> bf16. grid 32 x 256.
// ---------------------------------------------------------------------------
__global__ __launch_bounds__(256) void k_qprep0(
    const float* __restrict__ query, const float* __restrict__ lng,
    const float* __restrict__ lnb, const float* __restrict__ Wq,
    unsigned short* __restrict__ qn_g)
{
    __shared__ __align__(16) float xq[16 * 128];
    int b = blockIdx.x, tid = threadIdx.x;
    int n = tid >> 4, part = tid & 15;
    int row = b * 16 + n;
    const float4* x4 = (const float4*)(query + row * 128 + part * 8);
    float4 x0 = x4[0], x1 = x4[1];
    float s = x0.x + x0.y + x0.z + x0.w + x1.x + x1.y + x1.z + x1.w;
    float ss = x0.x * x0.x + x0.y * x0.y + x0.z * x0.z + x0.w * x0.w +
               x1.x * x1.x + x1.y * x1.y + x1.z * x1.z + x1.w * x1.w;
    s += __shfl_xor(s, 1); s += __shfl_xor(s, 2); s += __shfl_xor(s, 4); s += __shfl_xor(s, 8);
    ss += __shfl_xor(ss, 1); ss += __shfl_xor(ss, 2); ss += __shfl_xor(ss, 4); ss += __shfl_xor(ss, 8);
    float mean = s * (1.f / 128.f);
    float var = ss * (1.f / 128.f) - mean * mean;
    float rstd = rsqrtf(var + EPS_LN);
    const float4* g4 = (const float4*)(lng + part * 8);
    const float4* b4 = (const float4*)(lnb + part * 8);
    float4 g0 = g4[0], g1 = g4[1], bb0 = b4[0], bb1 = b4[1];
    float4 o0, o1;
    o0.x = (x0.x - mean) * rstd * g0.x + bb0.x;
    o0.y = (x0.y - mean) * rstd * g0.y + bb0.y;
    o0.z = (x0.z - mean) * rstd * g0.z + bb0.z;
    o0.w = (x0.w - mean) * rstd * g0.w + bb0.w;
    o1.x = (x1.x - mean) * rstd * g1.x + bb1.x;
    o1.y = (x1.y - mean) * rstd * g1.y + bb1.y;
    o1.z = (x1.z - mean) * rstd * g1.z + bb1.z;
    o1.w = (x1.w - mean) * rstd * g1.w + bb1.w;
    float4* xrow = (float4*)&xq[n * 128];
    xrow[part * 2] = o0;
    xrow[part * 2 + 1] = o1;
    __syncthreads();
    float o[8] = {0.f, 0.f, 0.f, 0.f, 0.f, 0.f, 0.f, 0.f};
    const float4* xv4 = (const float4*)&xq[n * 128];
#pragma unroll 4
    for (int j = 0; j < 32; j++) {
        float4 xv = xv4[j];
#pragma unroll
        for (int i = 0; i < 8; i++) {
            float4 w = ((const float4*)(Wq + (part * 8 + i) * 128))[j];
            o[i] += w.x * xv.x + w.y * xv.y + w.z * xv.z + w.w * xv.w;
        }
    }
    const float scale = 0.08838834764831845f;
#pragma unroll
    for (int i = 0; i < 8; i++)
        qn_g[row * 128 + part * 8 + i] = f2b(o[i] * scale);
}

// ---------------------------------------------------------------------------
// Kernel 1: kv = LN(inp); K = kv@Wk^T -> bf16 [b][hw][c];
//           V = kv@Wv^T -> bf16 transposed [b][c][hw]
// 64 rows/block, 256 threads. In-register LN (lane layout == A-frag layout).
// Weights staged in LDS with XOR swizzle (conflict-free b128 reads).
// K stores coalesced dwordx4 via LDS transpose buffer T.
// ---------------------------------------------------------------------------
__global__ __launch_bounds__(256) void k_kvproj(
    const float* __restrict__ inp, const float* __restrict__ lng,
    const float* __restrict__ lnb, const unsigned short* __restrict__ Wk_bf,
    const unsigned short* __restrict__ Wv_bf, unsigned short* __restrict__ Kbf,
    unsigned short* __restrict__ Vt)
{
    __shared__ __align__(16) unsigned short W_lds[128 * 128];  // swizzled weights, 32 KB
    __shared__ __align__(16) unsigned short T_lds[64 * 136];   // output staging, 17.4 KB
    const int tid = threadIdx.x;
    const int wave = tid >> 6, lane = tid & 63;
    const int l15 = lane & 15, q4 = lane >> 4;
    const int kof = q4 * 8;
    const int tile0 = blockIdx.x * 64;
    const int b = tile0 >> 12;
    const int hwbase = tile0 & (HW_ - 1);

    const int srow = tid >> 1, shalf = tid & 1;   // staging role: row, 8-chunk half
    const int sswz = srow & 7;

    // ---- in-register LN for this lane's row (tile0 + wave*16 + l15) ----
    float x[4][8];
    {
        const float* rowp = inp + (tile0 + (wave << 4) + l15) * C_;
        float s = 0.f, ss = 0.f;
#pragma unroll
        for (int ks = 0; ks < 4; ks++) {
#pragma unroll
            for (int h = 0; h < 2; h++) {
                float4 v = *(const float4*)(rowp + ks * 32 + kof + h * 4);
                x[ks][h * 4 + 0] = v.x; x[ks][h * 4 + 1] = v.y;
                x[ks][h * 4 + 2] = v.z; x[ks][h * 4 + 3] = v.w;
                s += v.x + v.y + v.z + v.w;
                ss += v.x * v.x + v.y * v.y + v.z * v.z + v.w * v.w;
            }
        }
        s += __shfl_xor(s, 16);  s += __shfl_xor(s, 32);
        ss += __shfl_xor(ss, 16); ss += __shfl_xor(ss, 32);
        float mean = s * (1.f / 128.f);
        float var = ss * (1.f / 128.f) - mean * mean;
        float rstd = rsqrtf(var + EPS_LN);
#pragma unroll
        for (int ks = 0; ks < 4; ks++) {
#pragma unroll
            for (int h = 0; h < 2; h++) {
                float4 g = *(const float4*)(lng + ks * 32 + kof + h * 4);
                float4 bb = *(const float4*)(lnb + ks * 32 + kof + h * 4);
                x[ks][h * 4 + 0] = (x[ks][h * 4 + 0] - mean) * rstd * g.x + bb.x;
                x[ks][h * 4 + 1] = (x[ks][h * 4 + 1] - mean) * rstd * g.y + bb.y;
                x[ks][h * 4 + 2] = (x[ks][h * 4 + 2] - mean) * rstd * g.z + bb.z;
                x[ks][h * 4 + 3] = (x[ks][h * 4 + 3] - mean) * rstd * g.w + bb.w;
            }
        }
    }
    // pack A-fragments
    short8 af[4];
#pragma unroll
    for (int ks = 0; ks < 4; ks++) {
        union { short8 s8; unsigned u[4]; } p;
#pragma unroll
        for (int j = 0; j < 4; j++)
            p.u[j] = (unsigned)f2b(x[ks][2 * j]) | ((unsigned)f2b(x[ks][2 * j + 1]) << 16);
        af[ks] = p.s8;
    }

    // ---- stage Wk (swizzled): thread covers row srow, chunks shalf*8+j ----
    {
        const uint4* gW = (const uint4*)Wk_bf;
#pragma unroll
        for (int j = 0; j < 8; j++) {
            int c = shalf * 8 + j;
            uint4 w = gW[srow * 16 + c];
            *(uint4*)&W_lds[srow * 128 + (c ^ sswz) * 8] = w;
        }
    }
    __syncthreads();

    f32x4 acc[8];
    // ---- K phase ----
#pragma unroll
    for (int nt = 0; nt < 8; nt++) {
        acc[nt] = (f32x4){0.f, 0.f, 0.f, 0.f};
#pragma unroll
        for (int ks = 0; ks < 4; ks++) {
            short8 bf = *(const short8*)&W_lds[(nt * 16 + l15) * 128 + ((ks * 4 + q4) ^ (l15 & 7)) * 8];
            acc[nt] = __builtin_amdgcn_mfma_f32_16x16x32_bf16(af[ks], bf, acc[nt], 0, 0, 0);
        }
    }
    // K acc -> T (per-wave private rows)
#pragma unroll
    for (int nt = 0; nt < 8; nt++) {
        int c = nt * 16 + l15;
#pragma unroll
        for (int i = 0; i < 4; i++)
            T_lds[((wave << 4) + (q4 << 2) + i) * 136 + c] = f2b(acc[nt][i]);
    }
    __syncthreads();   // T complete; Wk reads done
    // K coalesced stores + stage Wv
    {
        int row = tid >> 2, part = tid & 3;
        uint4 v0 = *(const uint4*)&T_lds[row * 136 + part * 32];
        uint4 v1 = *(const uint4*)&T_lds[row * 136 + part * 32 + 8];
        uint4* dst = (uint4*)&Kbf[(b * HW_ + hwbase + row) * C_ + part * 32];
        dst[0] = v0;
        dst[1] = v1;
    }
    {
        const uint4* gW = (const uint4*)Wv_bf;
#pragma unroll
        for (int j = 0; j < 8; j++) {
            int c = shalf * 8 + j;
            uint4 w = gW[srow * 16 + c];
            *(uint4*)&W_lds[srow * 128 + (c ^ sswz) * 8] = w;
        }
    }
    __syncthreads();
    // ---- V phase ----
#pragma unroll
    for (int nt = 0; nt < 8; nt++) {
        acc[nt] = (f32x4){0.f, 0.f, 0.f, 0.f};
#pragma unroll
        for (int ks = 0; ks < 4; ks++) {
            short8 bf = *(const short8*)&W_lds[(nt * 16 + l15) * 128 + ((ks * 4 + q4) ^ (l15 & 7)) * 8];
            acc[nt] = __builtin_amdgcn_mfma_f32_16x16x32_bf16(af[ks], bf, acc[nt], 0, 0, 0);
        }
    }
#pragma unroll
    for (int nt = 0; nt < 8; nt++) {
        int c = nt * 16 + l15;
#pragma unroll
        for (int i = 0; i < 4; i++)
            T_lds[((wave << 4) + (q4 << 2) + i) * 136 + c] = f2b(acc[nt][i]);
    }
    __syncthreads();
    // V transposed stores: thread -> (col c, 32 hw) packed to dwordx4
    {
        int c = tid >> 1, half = tid & 1;
        unsigned short* vbase = Vt + (b * C_ + c) * HW_ + hwbase + half * 32;
#pragma unroll
        for (int g = 0; g < 4; g++) {
            union { uint4 u4; unsigned u[4]; } p;
#pragma unroll
            for (int d = 0; d < 4; d++) {
                int h = half * 32 + g * 8 + d * 2;
                unsigned lo = T_lds[h * 136 + c];
                unsigned hi = T_lds[(h + 1) * 136 + c];
                p.u[d] = lo | (hi << 16);
            }
            *(uint4*)(vbase + g * 8) = p.u4;
        }
    }
}

// ---------------------------------------------------------------------------
// Kernel 2 (per iter): logits -> column softmax (16 slots) -> a0 ->
// per-chunk partial U / rowsum. grid (32, B): 128 hw/block, 32 hw/wave.
// qn precomputed (global bf16).
// ---------------------------------------------------------------------------
__global__ __launch_bounds__(256) void k_attn(
    const unsigned short* __restrict__ qn_g, const unsigned short* __restrict__ Kbf,
    const unsigned short* __restrict__ Vt, float* __restrict__ Upart,
    float* __restrict__ rspart, float* __restrict__ a0_out, int last)
{
    __shared__ __align__(16) float Ul[4][2048];            // 32 KB
    __shared__ __align__(16) unsigned short Pb[4][16 * 40];
    __shared__ float rsw[4][16];
    const int b = blockIdx.y, chunk = blockIdx.x;
    const int tid = threadIdx.x;
    const int wave = tid >> 6, lane = tid & 63;
    const int l15 = lane & 15, q4 = lane >> 4;
    const int kof = q4 * 8;
    const int hwb = chunk * 128 + wave * 32;

    short8 aq[4];
#pragma unroll
    for (int ks = 0; ks < 4; ks++)
        aq[ks] = *(const short8*)&qn_g[(b * 16 + l15) * 128 + ks * 32 + kof];

    unsigned short* Pw = &Pb[wave][0];
    float rs[4] = {0.f, 0.f, 0.f, 0.f};
#pragma unroll
    for (int s = 0; s < 2; s++) {
        int hwt = hwb + s * 16;
        f32x4 sa = {0.f, 0.f, 0.f, 0.f};
#pragma unroll
        for (int ks = 0; ks < 4; ks++) {
            short8 bk = *(const short8*)&Kbf[(b * HW_ + hwt + l15) * C_ + ks * 32 + kof];
            sa = __builtin_amdgcn_mfma_f32_16x16x32_bf16(aq[ks], bk, sa, 0, 0, 0);
        }
        float mx = fmaxf(fmaxf(sa[0], sa[1]), fmaxf(sa[2], sa[3]));
        mx = fmaxf(mx, __shfl_xor(mx, 16));
        mx = fmaxf(mx, __shfl_xor(mx, 32));
        float e[4]; float ssum = 0.f;
#pragma unroll
        for (int i = 0; i < 4; i++) { e[i] = __expf(sa[i] - mx); ssum += e[i]; }
        ssum += __shfl_xor(ssum, 16);
        ssum += __shfl_xor(ssum, 32);
        float inv = 1.f / ssum;
#pragma unroll
        for (int i = 0; i < 4; i++) {
            float a0v = e[i] * inv;
            rs[i] += a0v;
            if (last) a0_out[(b * 16 + q4 * 4 + i) * HW_ + hwt + l15] = a0v;
            Pw[(q4 * 4 + i) * 40 + s * 16 + l15] = f2b(a0v);
        }
    }
    // rowsum wave partial
#pragma unroll
    for (int i = 0; i < 4; i++) {
        rs[i] += __shfl_xor(rs[i], 1);
        rs[i] += __shfl_xor(rs[i], 2);
        rs[i] += __shfl_xor(rs[i], 4);
        rs[i] += __shfl_xor(rs[i], 8);
    }
    if (l15 == 0) {
#pragma unroll
        for (int i = 0; i < 4; i++) rsw[wave][q4 * 4 + i] = rs[i];
    }
    // u^T partial: same-wave P read (lgkmcnt handled by compiler, no barrier)
    short8 bp = *(const short8*)&Pw[l15 * 40 + kof];
#pragma unroll
    for (int ct = 0; ct < 8; ct++) {
        short8 av = *(const short8*)&Vt[(b * C_ + ct * 16 + l15) * HW_ + hwb + kof];
        f32x4 ua = __builtin_amdgcn_mfma_f32_16x16x32_bf16(av, bp, (f32x4){0.f, 0.f, 0.f, 0.f}, 0, 0, 0);
        int c = ct * 16 + q4 * 4;
#pragma unroll
        for (int i = 0; i < 4; i++)
            Ul[wave][(c + i) * 16 + l15] = ua[i];
    }
    __syncthreads();
    {
        float* up = Upart + (b * 32 + chunk) * 2048;
#pragma unroll
        for (int k = 0; k < 8; k++) {
            int idx = tid + k * 256;          // idx = c*16 + q
            up[idx] = Ul[0][idx] + Ul[1][idx] + Ul[2][idx] + Ul[3][idx];
        }
        if (tid < 16)
            rspart[(b * 32 + chunk) * 16 + tid] =
                rsw[0][tid] + rsw[1][tid] + rsw[2][tid] + rsw[3][tid];
    }
}

// ---------------------------------------------------------------------------
// Kernel 3 (per iter): u = (sum Upart)/(sum rspart + eps); y = GRU(u, h);
// z = LN2(y); q_new = y + FFN(z); and (if !last) qn_next = LN(q_new)@Wq^T*s.
// 2 rows/block, 256 threads. bf16 weights, fp32 math.
// ---------------------------------------------------------------------------
__global__ __launch_bounds__(256) void k_tail(
    const float* __restrict__ Upart, const float* __restrict__ rspart,
    const float* __restrict__ hsrc, float* __restrict__ q_buf,
    const unsigned short* __restrict__ wih_bf, const unsigned short* __restrict__ whh_bf,
    const float* __restrict__ bih, const float* __restrict__ bhh,
    const float* __restrict__ ln2g, const float* __restrict__ ln2b,
    const unsigned short* __restrict__ w1_bf, const float* __restrict__ b1,
    const unsigned short* __restrict__ w2_bf, const float* __restrict__ b2,
    const float* __restrict__ lnqg, const float* __restrict__ lnqb,
    const float* __restrict__ Wq, unsigned short* __restrict__ qn_g,
    float* __restrict__ out_q, int last)
{
    __shared__ __align__(16) float u_l[2][128];
    __shared__ __align__(16) float h_l[2][128];
    __shared__ __align__(16) float g_l[2][768];
    __shared__ __align__(16) float z_l[2][128];
    __shared__ __align__(16) float y_l[2][128];
    __shared__ __align__(16) float h1_l[2][512];
    __shared__ float stats[2][2];
    __shared__ float wpart[4][2];
    int tid = threadIdx.x;
    int row0 = blockIdx.x * 2;
    int r = tid >> 7, c = tid & 127;
    int row = row0 + r;
    {
        int bb = row >> 4, q = row & 15;
        float rsv = 0.f, uraw = 0.f;
#pragma unroll
        for (int ch = 0; ch < 32; ch++) {
            rsv  += rspart[(bb * 32 + ch) * 16 + q];
            uraw += Upart[(bb * 32 + ch) * 2048 + c * 16 + q];
        }
        u_l[r][c] = uraw / (rsv + EPS_ATTN);
        h_l[r][c] = hsrc[row * 128 + c];
    }
    __syncthreads();
    // GRU gates: 768 outputs, bf16 weights
#pragma unroll
    for (int o3 = 0; o3 < 3; o3++) {
        int o = tid + o3 * 256;
        const unsigned short* wrow;
        const float* srcbase;
        float bias;
        if (o < 384) { wrow = wih_bf + o * 128; srcbase = &u_l[0][0]; bias = bih[o]; }
        else         { wrow = whh_bf + (o - 384) * 128; srcbase = &h_l[0][0]; bias = bhh[o - 384]; }
        const uint4* w4 = (const uint4*)wrow;
        const float4* s0 = (const float4*)srcbase;
        const float4* s1 = (const float4*)(srcbase + 128);
        float a0acc = 0.f, a1acc = 0.f;
#pragma unroll 8
        for (int j = 0; j < 16; j++) {
            uint4 w = w4[j];
            float w0 = blo(w.x), w1v = bhi(w.x), w2v = blo(w.y), w3 = bhi(w.y);
            float w4v = blo(w.z), w5 = bhi(w.z), w6 = blo(w.w), w7 = bhi(w.w);
            float4 aA = s0[2 * j], aB = s0[2 * j + 1];
            float4 bA = s1[2 * j], bB = s1[2 * j + 1];
            a0acc += w0 * aA.x + w1v * aA.y + w2v * aA.z + w3 * aA.w
                   + w4v * aB.x + w5 * aB.y + w6 * aB.z + w7 * aB.w;
            a1acc += w0 * bA.x + w1v * bA.y + w2v * bA.z + w3 * bA.w
                   + w4v * bB.x + w5 * bB.y + w6 * bB.z + w7 * bB.w;
        }
        g_l[0][o] = a0acc + bias;
        g_l[1][o] = a1acc + bias;
    }
    __syncthreads();
    {
        float ir = g_l[r][c], iz = g_l[r][128 + c], in_ = g_l[r][256 + c];
        float hr = g_l[r][384 + c], hz = g_l[r][512 + c], hn = g_l[r][640 + c];
        float rr = 1.f / (1.f + expf(-(ir + hr)));
        float zz = 1.f / (1.f + expf(-(iz + hz)));
        float nn = tanhf(in_ + rr * hn);
        y_l[r][c] = (1.f - zz) * nn + zz * h_l[r][c];
    }
    __syncthreads();
    if (tid < 128) {
        int w = tid >> 6, ln = tid & 63;
        float v0 = y_l[w][ln], v1 = y_l[w][ln + 64];
        float s = v0 + v1, ss = v0 * v0 + v1 * v1;
#pragma unroll
        for (int off = 1; off < 64; off <<= 1) {
            s += __shfl_xor(s, off);
            ss += __shfl_xor(ss, off);
        }
        if (ln == 0) {
            float mean = s * (1.f / 128.f);
            float var = ss * (1.f / 128.f) - mean * mean;
            stats[w][0] = mean;
            stats[w][1] = rsqrtf(var + EPS_LN);
        }
    }
    __syncthreads();
    z_l[r][c] = (y_l[r][c] - stats[r][0]) * stats[r][1] * ln2g[c] + ln2b[c];
    __syncthreads();
    // FFN1 (bf16 w1)
#pragma unroll
    for (int f2i = 0; f2i < 2; f2i++) {
        int f = tid + f2i * 256;
        const uint4* w4 = (const uint4*)(w1_bf + f * 128);
        const float4* s0 = (const float4*)&z_l[0][0];
        const float4* s1 = (const float4*)&z_l[1][0];
        float a0acc = 0.f, a1acc = 0.f;
#pragma unroll 8
        for (int j = 0; j < 16; j++) {
            uint4 w = w4[j];
            float w0 = blo(w.x), w1v = bhi(w.x), w2v = blo(w.y), w3 = bhi(w.y);
            float w4v = blo(w.z), w5 = bhi(w.z), w6 = blo(w.w), w7 = bhi(w.w);
            float4 aA = s0[2 * j], aB = s0[2 * j + 1];
            float4 bA = s1[2 * j], bB = s1[2 * j + 1];
            a0acc += w0 * aA.x + w1v * aA.y + w2v * aA.z + w3 * aA.w
                   + w4v * aB.x + w5 * aB.y + w6 * aB.z + w7 * aB.w;
            a1acc += w0 * bA.x + w1v * bA.y + w2v * bA.z + w3 * bA.w
                   + w4v * bB.x + w5 * bB.y + w6 * bB.z + w7 * bB.w;
        }
        float bv = b1[f];
        h1_l[0][f] = fmaxf(a0acc + bv, 0.f);
        h1_l[1][f] = fmaxf(a1acc + bv, 0.f);
    }
    __syncthreads();
    // FFN2 + residual (bf16 w2)
    float q_new;
    {
        const uint4* w4 = (const uint4*)(w2_bf + c * 512);
        const float4* hh = (const float4*)&h1_l[r][0];
        float acc = 0.f;
#pragma unroll 8
        for (int j = 0; j < 64; j++) {
            uint4 w = w4[j];
            float4 hA = hh[2 * j], hB = hh[2 * j + 1];
            acc += blo(w.x) * hA.x + bhi(w.x) * hA.y + blo(w.y) * hA.z + bhi(w.y) * hA.w
                 + blo(w.z) * hB.x + bhi(w.z) * hB.y + blo(w.w) * hB.z + bhi(w.w) * hB.w;
        }
        q_new = y_l[r][c] + acc + b2[c];
        q_buf[row * 128 + c] = q_new;
        if (last) out_q[row * 128 + c] = q_new;
    }
    if (!last) {
        // fused qn for next iter: LN(q_new) @ Wq^T * scale
        __syncthreads();
        y_l[r][c] = q_new;   // reuse as q_new buffer
        __syncthreads();
        {
            int w = tid >> 6, ln = tid & 63;   // wave w covers row w>>1, half w&1
            float v = y_l[w >> 1][(w & 1) * 64 + ln];
            float s = v, ss = v * v;
#pragma unroll
            for (int off = 1; off < 64; off <<= 1) {
                s += __shfl_xor(s, off);
                ss += __shfl_xor(ss, off);
            }
            if (ln == 0) { wpart[w][0] = s; wpart[w][1] = ss; }
        }
        __syncthreads();
        {
            float s = wpart[2 * r][0] + wpart[2 * r + 1][0];
            float ss = wpart[2 * r][1] + wpart[2 * r + 1][1];
            float mean = s * (1.f / 128.f);
            float var = ss * (1.f / 128.f) - mean * mean;
            float rstd = rsqrtf(var + EPS_LN);
            z_l[r][c] = (q_new - mean) * rstd * lnqg[c] + lnqb[c];
        }
        __syncthreads();
        {
            const float4* w4 = (const float4*)(Wq + c * 128);
            const float4* zz = (const float4*)&z_l[r][0];
            float acc = 0.f;
#pragma unroll 8
            for (int j = 0; j < 32; j++) {
                float4 w = w4[j], v = zz[j];
                acc += w.x * v.x + w.y * v.y + w.z * v.z + w.w * v.w;
            }
            qn_g[row * 128 + c] = f2b(acc * 0.08838834764831845f);
        }
    }
}

// ---------------------------------------------------------------------------
extern "C" void kernel_launch(void* const* d_in, const int* in_sizes, int n_in,
                              void* d_out, int out_size, void* d_ws, size_t ws_size,
                              hipStream_t stream) {
    const float* inp     = (const float*)d_in[0];
    const float* query   = (const float*)d_in[1];
    const float* ln_kv_g = (const float*)d_in[2];
    const float* ln_kv_b = (const float*)d_in[3];
    const float* Wk      = (const float*)d_in[4];
    const float* Wv      = (const float*)d_in[5];
    const float* ln_q_g  = (const float*)d_in[6];
    const float* ln_q_b  = (const float*)d_in[7];
    const float* Wq      = (const float*)d_in[8];
    const float* gru_wih = (const float*)d_in[9];
    const float* gru_whh = (const float*)d_in[10];
    const float* gru_bih = (const float*)d_in[11];
    const float* gru_bhh = (const float*)d_in[12];
    const float* ln2_g   = (const float*)d_in[13];
    const float* ln2_b   = (const float*)d_in[14];
    const float* ffn_w1  = (const float*)d_in[15];
    const float* ffn_b1  = (const float*)d_in[16];
    const float* ffn_w2  = (const float*)d_in[17];
    const float* ffn_b2  = (const float*)d_in[18];

    char* ws = (char*)d_ws;
    unsigned short* Kbf    = (unsigned short*)ws;                  // 33554432
    unsigned short* Vt     = (unsigned short*)(ws + 33554432);     // 33554432
    float* q_buf           = (float*)(ws + 67108864);              // 262144
    float* Upart           = (float*)(ws + 67371008);              // 8388608
    float* rspart          = (float*)(ws + 75759616);              // 65536
    unsigned short* qn_g   = (unsigned short*)(ws + 75825152);     // 131072
    unsigned short* Wk_bf  = (unsigned short*)(ws + 75956224);     // 32768
    unsigned short* Wv_bf  = (unsigned short*)(ws + 75988992);     // 32768
    unsigned short* wih_bf = (unsigned short*)(ws + 76021760);     // 98304
    unsigned short* whh_bf = (unsigned short*)(ws + 76120064);     // 98304
    unsigned short* w1_bf  = (unsigned short*)(ws + 76218368);     // 131072
    unsigned short* w2_bf  = (unsigned short*)(ws + 76349440);     // 131072

    float* out_q  = (float*)d_out;
    float* out_a0 = out_q + B_ * N_ * C_;

    k_wprep<<<dim3(256), dim3(256), 0, stream>>>(
        Wk, Wv, gru_wih, gru_whh, ffn_w1, ffn_w2,
        Wk_bf, Wv_bf, wih_bf, whh_bf, w1_bf, w2_bf);
    k_qprep0<<<dim3(B_), dim3(256), 0, stream>>>(query, ln_q_g, ln_q_b, Wq, qn_g);
    k_kvproj<<<dim3((B_ * HW_) / 64), dim3(256), 0, stream>>>(
        inp, ln_kv_g, ln_kv_b, Wk_bf, Wv_bf, Kbf, Vt);

    for (int it = 0; it < ITERS_; it++) {
        int last = (it == ITERS_ - 1) ? 1 : 0;
        const float* hsrc = (it == 0) ? query : q_buf;
        k_attn<<<dim3(32, B_), dim3(256), 0, stream>>>(
            qn_g, Kbf, Vt, Upart, rspart, out_a0, last);
        k_tail<<<dim3((B_ * N_) / 2), dim3(256), 0, stream>>>(
            Upart, rspart, hsrc, q_buf, wih_bf, whh_bf, gru_bih, gru_bhh,
            ln2_g, ln2_b, w1_bf, ffn_b1, w2_bf, ffn_b2,
            ln_q_g, ln_q_b, Wq, qn_g, out_q, last);
    }
}